// Round 1
// baseline (572.134 us; speedup 1.0000x reference)
//
#include <hip/hip_runtime.h>

#ifndef __has_builtin
#define __has_builtin(x) 0
#endif

// 2^x via v_exp_f32 (native, ~1 ulp)
__device__ __forceinline__ float fexp2(float x) {
#if __has_builtin(__builtin_amdgcn_exp2f)
    return __builtin_amdgcn_exp2f(x);
#else
    float r; asm volatile("v_exp_f32 %0, %1" : "=v"(r) : "v"(x)); return r;
#endif
}

// 1/x via v_rcp_f32 (native approx, ~1 ulp — plenty for 40 normalization passes)
__device__ __forceinline__ float frcp(float x) {
#if __has_builtin(__builtin_amdgcn_rcpf)
    return __builtin_amdgcn_rcpf(x);
#else
    float r; asm volatile("v_rcp_f32 %0, %1" : "=v"(r) : "v"(x)); return r;
#endif
}

// 1 / (SINKHORN_TEMP * ln2): converts (gamma+noise)/temp natural-log-space
// initialization into a single native exp2.
#define KSC 7.2134752044448170f

// One block per batch matrix. 256 threads = 16x16 thread grid; thread (ty,tx)
// owns an 8x8 register tile: rows [8*ty, 8*ty+8), cols [8*tx, 8*tx+8).
// Linear-space Sinkhorn: row pass = divide each row by its sum, col pass =
// divide each col by its sum. Row reduce: in-thread + shfl_xor over tx bits
// (1,2,4,8). Col reduce: in-thread + shfl_xor over lane bits (16,32) + LDS
// exchange across the 4 waves.
__global__ void __launch_bounds__(256)
lp_sinkhorn(const float* __restrict__ gamma,
            const float* __restrict__ noise,
            const int* __restrict__ itp,
            float* __restrict__ out)
{
    const int b    = blockIdx.x;
    const int t    = threadIdx.x;
    const int tx   = t & 15;
    const int ty   = t >> 4;
    const int wv   = t >> 6;
    const int lane = t & 63;
    const int niter = itp[0];

    __shared__ float part[4][128];

    const int row0 = ty << 3;
    const int col0 = tx << 3;

    const float* gbase = gamma + row0 * 128 + col0;
    const float* nbase = noise + ((size_t)b << 14) + row0 * 128 + col0;
    float*       obase = out   + ((size_t)b << 14) + row0 * 128 + col0;

    float e[8][8];

    // ---- load + fused (gamma + noise)/temp, exp to linear space ----
#pragma unroll
    for (int r = 0; r < 8; ++r) {
        float4 g0 = *reinterpret_cast<const float4*>(gbase + r * 128);
        float4 g1 = *reinterpret_cast<const float4*>(gbase + r * 128 + 4);
        float4 u0 = *reinterpret_cast<const float4*>(nbase + r * 128);
        float4 u1 = *reinterpret_cast<const float4*>(nbase + r * 128 + 4);
        e[r][0] = fexp2((g0.x + u0.x) * KSC);
        e[r][1] = fexp2((g0.y + u0.y) * KSC);
        e[r][2] = fexp2((g0.z + u0.z) * KSC);
        e[r][3] = fexp2((g0.w + u0.w) * KSC);
        e[r][4] = fexp2((g1.x + u1.x) * KSC);
        e[r][5] = fexp2((g1.y + u1.y) * KSC);
        e[r][6] = fexp2((g1.z + u1.z) * KSC);
        e[r][7] = fexp2((g1.w + u1.w) * KSC);
    }

    for (int it = 0; it < niter; ++it) {
        // ---------- row normalize (sum over columns, per row) ----------
#pragma unroll
        for (int r = 0; r < 8; ++r) {
            float s = ((e[r][0] + e[r][1]) + (e[r][2] + e[r][3]))
                    + ((e[r][4] + e[r][5]) + (e[r][6] + e[r][7]));
            s += __shfl_xor(s, 1);
            s += __shfl_xor(s, 2);
            s += __shfl_xor(s, 4);
            s += __shfl_xor(s, 8);
            const float rinv = frcp(s);
#pragma unroll
            for (int c = 0; c < 8; ++c) e[r][c] *= rinv;
        }

        // ---------- col normalize (sum over rows, per column) ----------
        float cs[8];
#pragma unroll
        for (int c = 0; c < 8; ++c) {
            float v = ((e[0][c] + e[1][c]) + (e[2][c] + e[3][c]))
                    + ((e[4][c] + e[5][c]) + (e[6][c] + e[7][c]));
            v += __shfl_xor(v, 16);   // combine ty-in-wave groups
            v += __shfl_xor(v, 32);
            cs[c] = v;                // per-wave partial col sum (all lanes hold it)
        }

        __syncthreads();              // prior iteration's part[] reads complete
        if (lane < 16) {              // one ty-group per wave writes partials
            *reinterpret_cast<float4*>(&part[wv][col0])
                = make_float4(cs[0], cs[1], cs[2], cs[3]);
            *reinterpret_cast<float4*>(&part[wv][col0 + 4])
                = make_float4(cs[4], cs[5], cs[6], cs[7]);
        }
        __syncthreads();

        const float4 p00 = *reinterpret_cast<const float4*>(&part[0][col0]);
        const float4 p01 = *reinterpret_cast<const float4*>(&part[0][col0 + 4]);
        const float4 p10 = *reinterpret_cast<const float4*>(&part[1][col0]);
        const float4 p11 = *reinterpret_cast<const float4*>(&part[1][col0 + 4]);
        const float4 p20 = *reinterpret_cast<const float4*>(&part[2][col0]);
        const float4 p21 = *reinterpret_cast<const float4*>(&part[2][col0 + 4]);
        const float4 p30 = *reinterpret_cast<const float4*>(&part[3][col0]);
        const float4 p31 = *reinterpret_cast<const float4*>(&part[3][col0 + 4]);

        float ci[8];
        ci[0] = frcp((p00.x + p10.x) + (p20.x + p30.x));
        ci[1] = frcp((p00.y + p10.y) + (p20.y + p30.y));
        ci[2] = frcp((p00.z + p10.z) + (p20.z + p30.z));
        ci[3] = frcp((p00.w + p10.w) + (p20.w + p30.w));
        ci[4] = frcp((p01.x + p11.x) + (p21.x + p31.x));
        ci[5] = frcp((p01.y + p11.y) + (p21.y + p31.y));
        ci[6] = frcp((p01.z + p11.z) + (p21.z + p31.z));
        ci[7] = frcp((p01.w + p11.w) + (p21.w + p31.w));

#pragma unroll
        for (int r = 0; r < 8; ++r) {
#pragma unroll
            for (int c = 0; c < 8; ++c) e[r][c] *= ci[c];
        }
    }

    // ---- store: out = exp(log_alpha) == current linear-space e ----
#pragma unroll
    for (int r = 0; r < 8; ++r) {
        *reinterpret_cast<float4*>(obase + r * 128)
            = make_float4(e[r][0], e[r][1], e[r][2], e[r][3]);
        *reinterpret_cast<float4*>(obase + r * 128 + 4)
            = make_float4(e[r][4], e[r][5], e[r][6], e[r][7]);
    }
}

extern "C" void kernel_launch(void* const* d_in, const int* in_sizes, int n_in,
                              void* d_out, int out_size, void* d_ws, size_t ws_size,
                              hipStream_t stream) {
    const float* gamma = (const float*)d_in[0];
    const float* noise = (const float*)d_in[1];
    const int*   itp   = (const int*)d_in[2];
    float*       out   = (float*)d_out;

    const int B = in_sizes[1] / (128 * 128);   // 4096

    hipLaunchKernelGGL(lp_sinkhorn, dim3(B), dim3(256), 0, stream,
                       gamma, noise, itp, out);
}